// Round 14
// baseline (245.636 us; speedup 1.0000x reference)
//
#include <hip/hip_runtime.h>
#include <stdint.h>

typedef unsigned short u16;
typedef unsigned int u32;
typedef __bf16 bf16x8 __attribute__((ext_vector_type(8)));
typedef float f32x4 __attribute__((ext_vector_type(4)));
typedef unsigned short ushort8 __attribute__((ext_vector_type(8)));

#define QSCALE 0.1803368801111244f   // 64^-0.5 * log2(e): S comes out in log2 domain
#define M0 18.0f                     // fixed softmax "max" in log2 domain (true |s| <~ 12)

// ---------- helpers ----------
__device__ __forceinline__ u16 f2bf(float f) {
  union { float f; unsigned u; } v; v.f = f;
  return (u16)((v.u + 0x7FFFu + ((v.u >> 16) & 1u)) >> 16);
}

__device__ __forceinline__ void gl_lds16(const void* g, void* l) {
  typedef __attribute__((address_space(1))) void* gp_t;
  typedef __attribute__((address_space(3))) void* lp_t;
  __builtin_amdgcn_global_load_lds((gp_t)(g), (lp_t)(l), 16, 0, 0);
}

union BF8 { u32 u[4]; bf16x8 v; };
union FU { float f; u32 u; };

// ---------- fused fp32 -> bf16 converts (hidden states + 4 weight matrices) ----------
__global__ void __launch_bounds__(256) cvt_all(const float* __restrict__ hs,
                                               const float* __restrict__ Wq,
                                               const float* __restrict__ Wk,
                                               const float* __restrict__ Wv,
                                               const float* __restrict__ Wo,
                                               u16* __restrict__ Hb,
                                               u16* __restrict__ Wqkv) {
  int bid = blockIdx.x;
  const float* src;
  u16* dst;
  int i;
  if (bid < 2048) {
    i = (bid * 256 + threadIdx.x) * 8;
    src = hs + i;
    dst = Hb + i;
  } else {
    i = ((bid - 2048) * 256 + threadIdx.x) * 8;
    int sel = i >> 20;
    const float* w = (sel == 0) ? Wq : (sel == 1) ? Wk : (sel == 2) ? Wv : Wo;
    src = w + (i & 1048575);
    dst = Wqkv + i;
  }
  float4 f0 = *(const float4*)(src);
  float4 f1 = *(const float4*)(src + 4);
  ushort8 o;
  o[0] = f2bf(f0.x); o[1] = f2bf(f0.y); o[2] = f2bf(f0.z); o[3] = f2bf(f0.w);
  o[4] = f2bf(f1.x); o[5] = f2bf(f1.y); o[6] = f2bf(f1.z); o[7] = f2bf(f1.w);
  *(ushort8*)(dst) = o;
}

// ---------- templated MT x NT GEMM core: C = A @ W^T, K=1024, BK=64 ----------
// 256 threads = 4 waves in 2x2. XOR-swizzled LDS (slot s in row r holds chunk s^(r&7)).
// Depth-2 counted-vmcnt pipeline (T4). Each stage = 6 gl_lds16/thread (4 A + 2 B).
// MEASURED LADDER — the 2-phase family is CLOSED (do not re-try):
//   128x128 tile: R1 62.2, R6 56.6 | BK=32: R9 61.4 | depth-3: R12 54.5
//   no LDS stage: R7 attn 128 (8x traffic) | n-fastest: R8 FETCH 39->53 MB
// This config (BK=64, 128x64, depth-2, m-fastest, 3 blocks/CU) = 46.3-48.4 us on qkv.
template <int MT, int NT>
__device__ __forceinline__ void gemm_core_t(const u16* __restrict__ A, const u16* __restrict__ W,
                                            u16* As, u16* Bs,
                                            f32x4 (&acc)[MT / 32][NT / 32],
                                            int m0, int n0) {
  constexpr int AG = MT / 32, BG = NT / 32;   // staging groups AND frag count per wave
  constexpr int ASZ = MT * 64, BSZ = NT * 64; // elements per buffer
  static_assert(AG + BG == 6, "vmcnt literals assume 6 loads per stage");
  const int tid  = threadIdx.x;
  const int w    = tid >> 6, lane = tid & 63;
  const int wm   = (w >> 1) * (MT / 2), wn = (w & 1) * (NT / 2);
  const int srow = lane >> 3;
  const int slc  = ((lane & 7) ^ (srow & 7)) * 8;
  const int q4   = lane >> 4, c = lane & 15;

  auto stage = [&](int k0, int pb) {
#pragma unroll
    for (int qq = 0; qq < AG; ++qq) {
      int chunk = w * AG + qq;
      gl_lds16(A + (size_t)(m0 + chunk * 8 + srow) * 1024 + k0 + slc,
               As + pb * ASZ + chunk * 512);
    }
#pragma unroll
    for (int qq = 0; qq < BG; ++qq) {
      int chunk = w * BG + qq;
      gl_lds16(W + (size_t)(n0 + chunk * 8 + srow) * 1024 + k0 + slc,
               Bs + pb * BSZ + chunk * 512);
    }
  };

  stage(0, 0);     // 6 loads in flight
  stage(64, 1);    // 12 in flight

  for (int it = 0; it < 16; ++it) {
    const int cur = it & 1;
    // wait for stage(it)'s 6 loads; leave stage(it+1)'s 6 in flight
    if (it < 15) asm volatile("s_waitcnt vmcnt(6)" ::: "memory");
    else         asm volatile("s_waitcnt vmcnt(0)" ::: "memory");
    __builtin_amdgcn_sched_barrier(0);
    __builtin_amdgcn_s_barrier();   // all waves' stage(it) now visible

    const u16* Ab = As + cur * ASZ;
    const u16* Bb = Bs + cur * BSZ;
#pragma unroll
    for (int ks = 0; ks < 2; ++ks) {
      bf16x8 af[AG], bfr[BG];
#pragma unroll
      for (int i = 0; i < AG; ++i) {
        int row = wm + i * 16 + c;
        af[i] = *(const bf16x8*)(Ab + row * 64 + (((ks * 4 + q4) ^ (row & 7)) * 8));
      }
#pragma unroll
      for (int j = 0; j < BG; ++j) {
        int row = wn + j * 16 + c;
        bfr[j] = *(const bf16x8*)(Bb + row * 64 + (((ks * 4 + q4) ^ (row & 7)) * 8));
      }
      __builtin_amdgcn_s_setprio(1);
#pragma unroll
      for (int i = 0; i < AG; ++i)
#pragma unroll
        for (int j = 0; j < BG; ++j)
          acc[i][j] = __builtin_amdgcn_mfma_f32_16x16x32_bf16(af[i], bfr[j], acc[i][j], 0, 0, 0);
      __builtin_amdgcn_s_setprio(0);
    }

    if (it < 14) {
      __builtin_amdgcn_s_barrier();   // all waves done reading buf cur
      stage((it + 2) * 64, cur);      // refill it; lands by iteration it+2's wait
    }
  }
}

// ---------- fused QKV projection: one GEMM vs [Wq;Wk;Wv] (N=3072), tile 128x64 ----------
// Grid dim3(32m, 48n), m on x (fastest): consecutively-dispatched blocks share the same
// 128 KB W-panel. z = n0>>10 selects output: 0 -> Q (pre-scaled), 1 -> K, 2 -> V^T sigma.
__global__ void __launch_bounds__(256) qkv_gemm(const u16* __restrict__ Hb,
                                                const u16* __restrict__ Wqkv,
                                                u16* __restrict__ Q, u16* __restrict__ K,
                                                u16* __restrict__ Vt) {
  __shared__ u16 As[2 * 128 * 64];
  __shared__ u16 Bs[2 * 64 * 64];
  f32x4 acc[4][2];
#pragma unroll
  for (int i = 0; i < 4; ++i)
#pragma unroll
    for (int j = 0; j < 2; ++j) { f32x4 zv = {0.f, 0.f, 0.f, 0.f}; acc[i][j] = zv; }

  const int m0 = blockIdx.x * 128, n0g = blockIdx.y * 64;
  gemm_core_t<128, 64>(Hb, Wqkv, As, Bs, acc, m0, n0g);

  const int z = n0g >> 10, nl0 = n0g & 1023;
  const int tid = threadIdx.x, w = tid >> 6, lane = tid & 63;
  const int wm = (w >> 1) * 64, wn = (w & 1) * 32;
  const int q4 = lane >> 4, c = lane & 15;

#pragma unroll
  for (int i = 0; i < 4; ++i)
#pragma unroll
    for (int j = 0; j < 2; ++j)
#pragma unroll
      for (int r = 0; r < 4; ++r) {
        int m = m0 + wm + i * 16 + q4 * 4 + r;       // b*2048 + s
        int n = nl0 + wn + j * 16 + c;               // h*64 + d (within 1024)
        if (z == 0) {
          Q[(size_t)m * 1024 + n] = f2bf(acc[i][j][r] * QSCALE);
        } else if (z == 1) {
          K[(size_t)m * 1024 + n] = f2bf(acc[i][j][r]);
        } else {
          int b = m >> 11, s = m & 2047, h = n >> 6, d = n & 63;
          int kv = s & 127;
          int sig = ((kv >> 5) << 5) | (((kv >> 2) & 3) << 3) | (((kv >> 4) & 1) << 2) | (kv & 3);
          int sp = (s & ~127) | sig;
          Vt[(((size_t)(b * 16 + h) * 64 + d) << 11) + sp] = f2bf(acc[i][j][r]);
        }
      }
}

// ---------- fused attention + output projection (R14) ----------
// Phase 1: flash attention (4 waves, 32 q/wave, K/V LDS dbuf, counted vmcnt, ones-MFMA
// l-sum, head-pinned XCD decode) — identical math to R11's attn.
// Grid barrier: 512 blocks x 64 KB LDS -> EXACTLY 2 blocks/CU x 256 CU = 512 co-resident,
// so an arrive-and-spin barrier on a device-scope atomic cannot starve. Block 0 zeroes the
// counter at kernel start (~40 us of attn work precedes any arrival -> no race; also makes
// the kernel self-contained under rocprof single-dispatch replay). Cross-XCD visibility of
// O: producers' stores drain at __syncthreads (vmcnt), thread0 issues __threadfence()
// (agent-release, L2 writeback) before arriving; after the spin, __threadfence()
// (agent-acquire, cache invalidate) before consuming O.
// Phase 2: out = O @ Wo^T + bo, tile 128x64, same gemm core, smem reused.
__global__ void __launch_bounds__(256, 2) attn_out(const u16* __restrict__ Q,
                                                   const u16* __restrict__ K,
                                                   const u16* __restrict__ Vt,
                                                   u16* __restrict__ O,
                                                   const u16* __restrict__ Wo,
                                                   const float* __restrict__ bias,
                                                   float* __restrict__ Cout,
                                                   u32* bar) {
  __shared__ __align__(16) char smem[65536];
  u16* KsB = (u16*)smem;              // phase1: [2][128*64] = 32 KB
  u16* VsB = (u16*)(smem + 32768);    // phase1: [2][64*128] = 32 KB

  const int tid = threadIdx.x, w = tid >> 6, lane = tid & 63;
  const int q4 = lane >> 4, c = lane & 15;
  const int bid = blockIdx.x;

  if (bid == 0 && tid == 0) atomicExch(bar, 0u);   // self-init; see header comment

  // head-pinned decode: bid = 8*((bh>>3)*16 + qt) + (bh&7)
  const int qt = (bid >> 3) & 15;
  const int bh = ((bid >> 7) << 3) | (bid & 7);
  const int b = bh >> 4, h = bh & 15;

  const size_t qkbase = ((size_t)b * 2048) * 1024 + h * 64;   // [B,S,H,dh]
  const size_t vtbase = ((size_t)(b * 16 + h) * 64) * 2048;   // [B,H,dh,S']
  const int qbase = qt * 128 + w * 32;

  // Q fragments (B-operand: n=q=c, k=d=q4*8+j), resident all of phase 1
  bf16x8 qf[2][2];
#pragma unroll
  for (int t2 = 0; t2 < 2; ++t2)
#pragma unroll
    for (int ks = 0; ks < 2; ++ks)
      qf[t2][ks] = *(const bf16x8*)(Q + qkbase + (size_t)(qbase + t2 * 16 + c) * 1024 +
                                    ks * 32 + q4 * 8);

  // all-ones bf16 A-fragment for the l-sum MFMA
  BF8 onesu;
  onesu.u[0] = 0x3F803F80u; onesu.u[1] = 0x3F803F80u;
  onesu.u[2] = 0x3F803F80u; onesu.u[3] = 0x3F803F80u;
  const bf16x8 ones = onesu.v;

  f32x4 lacc[2];
  f32x4 oacc[2][4];
#pragma unroll
  for (int t2 = 0; t2 < 2; ++t2) {
    f32x4 zv = {0.f, 0.f, 0.f, 0.f};
    lacc[t2] = zv;
#pragma unroll
    for (int dt = 0; dt < 4; ++dt) oacc[t2][dt] = zv;
  }

  // staging indices: thread handles physical chunks ci = i*256 + tid, i=0..3
  int krow[4], klc[4], vrow[4], vlc[4];
#pragma unroll
  for (int i = 0; i < 4; ++i) {
    int ci = i * 256 + w * 64 + lane;
    krow[i] = ci >> 3; klc[i] = ((ci & 7) ^ (krow[i] & 7)) * 8;
    vrow[i] = ci >> 4; vlc[i] = ((ci & 15) ^ (vrow[i] & 15)) * 8;
  }

  auto stage = [&](int kt, int pb) {
#pragma unroll
    for (int i = 0; i < 4; ++i) {
      gl_lds16(K + qkbase + (size_t)(kt * 128 + krow[i]) * 1024 + klc[i],
               KsB + pb * 8192 + (i * 256 + w * 64) * 8);
      gl_lds16(Vt + vtbase + (size_t)vrow[i] * 2048 + kt * 128 + vlc[i],
               VsB + pb * 8192 + (i * 256 + w * 64) * 8);
    }
  };

  stage(0, 0);   // 8 loads in flight
  stage(1, 1);   // 16 in flight

  for (int kt = 0; kt < 16; ++kt) {
    const int cur = kt & 1;
    // wait for stage(kt)'s 8 loads; leave stage(kt+1)'s 8 in flight
    if (kt < 15) asm volatile("s_waitcnt vmcnt(8)" ::: "memory");
    else         asm volatile("s_waitcnt vmcnt(0)" ::: "memory");
    __builtin_amdgcn_sched_barrier(0);
    __builtin_amdgcn_s_barrier();   // all waves' stage(kt) now visible

    // S^T - M0 = K Q^T - M0 : C[row=kv (q4*4+r), col=q=c], log2 domain (Q pre-scaled)
    f32x4 sacc[2][8];
#pragma unroll
    for (int t2 = 0; t2 < 2; ++t2)
#pragma unroll
      for (int a = 0; a < 8; ++a) { f32x4 iv = {-M0, -M0, -M0, -M0}; sacc[t2][a] = iv; }
    __builtin_amdgcn_s_setprio(1);
#pragma unroll
    for (int ks = 0; ks < 2; ++ks) {
#pragma unroll
      for (int a = 0; a < 8; ++a) {
        bf16x8 kf = *(const bf16x8*)(KsB + cur * 8192 + (a * 16 + c) * 64 +
                                     (((ks * 4 + q4) ^ (c & 7)) * 8));
        sacc[0][a] = __builtin_amdgcn_mfma_f32_16x16x32_bf16(kf, qf[0][ks], sacc[0][a], 0, 0, 0);
        sacc[1][a] = __builtin_amdgcn_mfma_f32_16x16x32_bf16(kf, qf[1][ks], sacc[1][a], 0, 0, 0);
      }
    }
    __builtin_amdgcn_s_setprio(0);

    // p = exp2(sacc); pack high halves (truncate to bf16) straight into MFMA B-operands
    u32 pk[2][8][2];
#pragma unroll
    for (int t2 = 0; t2 < 2; ++t2) {
#pragma unroll
      for (int a = 0; a < 8; ++a) {
        FU p0, p1, p2, p3;
        p0.f = __builtin_amdgcn_exp2f(sacc[t2][a][0]);
        p1.f = __builtin_amdgcn_exp2f(sacc[t2][a][1]);
        p2.f = __builtin_amdgcn_exp2f(sacc[t2][a][2]);
        p3.f = __builtin_amdgcn_exp2f(sacc[t2][a][3]);
        pk[t2][a][0] = __builtin_amdgcn_perm(p1.u, p0.u, 0x07060302u);
        pk[t2][a][1] = __builtin_amdgcn_perm(p3.u, p2.u, 0x07060302u);
      }
    }

    // O^T += V^T P^T ; l += 1^T P^T (same pk registers -> exactly consistent)
    __builtin_amdgcn_s_setprio(1);
#pragma unroll
    for (int kch = 0; kch < 4; ++kch) {
      BF8 pf0, pf1;
      pf0.u[0] = pk[0][2 * kch][0];     pf0.u[1] = pk[0][2 * kch][1];
      pf0.u[2] = pk[0][2 * kch + 1][0]; pf0.u[3] = pk[0][2 * kch + 1][1];
      pf1.u[0] = pk[1][2 * kch][0];     pf1.u[1] = pk[1][2 * kch][1];
      pf1.u[2] = pk[1][2 * kch + 1][0]; pf1.u[3] = pk[1][2 * kch + 1][1];
      lacc[0] = __builtin_amdgcn_mfma_f32_16x16x32_bf16(ones, pf0.v, lacc[0], 0, 0, 0);
      lacc[1] = __builtin_amdgcn_mfma_f32_16x16x32_bf16(ones, pf1.v, lacc[1], 0, 0, 0);
#pragma unroll
      for (int dt = 0; dt < 4; ++dt) {
        bf16x8 vf = *(const bf16x8*)(VsB + cur * 8192 + (dt * 16 + c) * 128 +
                                     (((kch * 4 + q4) ^ c) * 8));
        oacc[0][dt] = __builtin_amdgcn_mfma_f32_16x16x32_bf16(vf, pf0.v, oacc[0][dt], 0, 0, 0);
        oacc[1][dt] = __builtin_amdgcn_mfma_f32_16x16x32_bf16(vf, pf1.v, oacc[1][dt], 0, 0, 0);
      }
    }
    __builtin_amdgcn_s_setprio(0);

    if (kt < 14) {
      __builtin_amdgcn_s_barrier();   // all waves done reading buf cur
      stage(kt + 2, cur);             // refill; lands by iteration kt+2's wait
    }
  }

  // lacc rows are identical (ones A): every lane holds l[its q] directly.
#pragma unroll
  for (int t2 = 0; t2 < 2; ++t2) {
    const float inv = 1.0f / lacc[t2][0];
    const size_t rowbase = qkbase + (size_t)(qbase + t2 * 16 + c) * 1024;
#pragma unroll
    for (int dt = 0; dt < 4; ++dt) {
      ushort4 o;
      o.x = f2bf(oacc[t2][dt][0] * inv);
      o.y = f2bf(oacc[t2][dt][1] * inv);
      o.z = f2bf(oacc[t2][dt][2] * inv);
      o.w = f2bf(oacc[t2][dt][3] * inv);
      *(ushort4*)(O + rowbase + dt * 16 + q4 * 4) = o;
    }
  }

  // ---- grid barrier: all O written -> visible device-wide -> reuse smem ----
  __syncthreads();                       // drains this block's O stores (vmcnt at barrier)
  if (tid == 0) {
    __threadfence();                     // agent-release: writeback L2 so other XCDs see O
    atomicAdd(bar, 1u);
    while (atomicAdd(bar, 0u) < 512u) {} // all 512 blocks co-resident -> terminates
  }
  __syncthreads();
  __threadfence();                       // agent-acquire: invalidate caches before reading O

  // ---- phase 2: out = O @ Wo^T + bo, tile 128x64 (m-fastest decode) ----
  u16* As = (u16*)smem;                  // 2*128*64 u16 = 32 KB
  u16* Bs = (u16*)(smem + 32768);        // 2*64*64 u16 = 16 KB
  f32x4 acc[4][2];
#pragma unroll
  for (int i = 0; i < 4; ++i)
#pragma unroll
    for (int j = 0; j < 2; ++j) { f32x4 zv = {0.f, 0.f, 0.f, 0.f}; acc[i][j] = zv; }

  const int m0 = (bid & 31) * 128, n0 = (bid >> 5) * 64;
  gemm_core_t<128, 64>(O, Wo, As, Bs, acc, m0, n0);

  const int wm = (w >> 1) * 64, wn = (w & 1) * 32;
#pragma unroll
  for (int j = 0; j < 2; ++j) {
    int n = n0 + wn + j * 16 + c;
    float bv = bias[n];
#pragma unroll
    for (int i = 0; i < 4; ++i)
#pragma unroll
      for (int r = 0; r < 4; ++r) {
        int m = m0 + wm + i * 16 + q4 * 4 + r;
        Cout[(size_t)m * 1024 + n] = acc[i][j][r] + bv;
      }
  }
}

// ---------- launch ----------
extern "C" void kernel_launch(void* const* d_in, const int* in_sizes, int n_in,
                              void* d_out, int out_size, void* d_ws, size_t ws_size,
                              hipStream_t stream) {
  const float* hs = (const float*)d_in[0];
  const float* Wq = (const float*)d_in[1];
  const float* Wk = (const float*)d_in[2];
  const float* Wv = (const float*)d_in[3];
  const float* Wo = (const float*)d_in[4];
  const float* bo = (const float*)d_in[5];
  float* out = (float*)d_out;

  u16* Hb   = (u16*)d_ws;            // 4096*1024
  u16* Wqkv = Hb + 4096 * 1024;      // [3072,1024]: Wq, Wk, Wv contiguous
  u16* Wob  = Wqkv + 3 * 1024 * 1024;
  u16* Qw   = Wob + 1024 * 1024;     // [B,S,H,dh], pre-scaled by QSCALE
  u16* Kw   = Qw + 4096 * 1024;      // [B,S,H,dh]
  u16* Vtw  = Kw + 4096 * 1024;      // [B,H,dh,S'] sigma-permuted
  u16* Ow   = Vtw + 4096 * 1024;     // [B,S,H,dh]
  u32* bar  = (u32*)(Ow + 4096 * 1024);  // 4 B grid-barrier counter (ws >= 48 MB + 4 B)

  cvt_all<<<4096, 256, 0, stream>>>(hs, Wq, Wk, Wv, Wo, Hb, Wqkv);

  qkv_gemm<<<dim3(32, 48), 256, 0, stream>>>(Hb, Wqkv, Qw, Kw, Vtw);
  attn_out<<<512, 256, 0, stream>>>(Qw, Kw, Vtw, Ow, Wob, bo, out, bar);
}

// Round 15
// 177.188 us; speedup vs baseline: 1.3863x; 1.3863x over previous
//
#include <hip/hip_runtime.h>
#include <stdint.h>

typedef unsigned short u16;
typedef unsigned int u32;
typedef __bf16 bf16x8 __attribute__((ext_vector_type(8)));
typedef float f32x4 __attribute__((ext_vector_type(4)));

#define QSCALE 0.1803368801111244f   // 64^-0.5 * log2(e): S comes out in log2 domain
#define M0 18.0f                     // fixed softmax "max" in log2 domain (true |s| <~ 12)

// ---------- helpers ----------
__device__ __forceinline__ u16 f2bf(float f) {
  union { float f; unsigned u; } v; v.f = f;
  return (u16)((v.u + 0x7FFFu + ((v.u >> 16) & 1u)) >> 16);
}

__device__ __forceinline__ void gl_lds16(const void* g, void* l) {
  typedef __attribute__((address_space(1))) void* gp_t;
  typedef __attribute__((address_space(3))) void* lp_t;
  __builtin_amdgcn_global_load_lds((gp_t)(g), (lp_t)(l), 16, 0, 0);
}

union BF8 { u32 u[4]; bf16x8 v; };
union FU { float f; u32 u; };

// ---------- fused fp32 -> bf16 converts (hidden states + 4 weight matrices) ----------
__global__ void __launch_bounds__(256) cvt_all(const float* __restrict__ hs,
                                               const float* __restrict__ Wq,
                                               const float* __restrict__ Wk,
                                               const float* __restrict__ Wv,
                                               const float* __restrict__ Wo,
                                               u16* __restrict__ Hb,
                                               u16* __restrict__ Wqkv) {
  int bid = blockIdx.x;
  if (bid < 4096) {
    int i = (bid * 256 + threadIdx.x) * 4;
    float4 f = *(const float4*)(hs + i);
    ushort4 o;
    o.x = f2bf(f.x); o.y = f2bf(f.y); o.z = f2bf(f.z); o.w = f2bf(f.w);
    *(ushort4*)(Hb + i) = o;
  } else {
    int i = ((bid - 4096) * 256 + threadIdx.x) * 4;
    int sel = i >> 20;
    const float* src = (sel == 0) ? Wq : (sel == 1) ? Wk : (sel == 2) ? Wv : Wo;
    float4 f = *(const float4*)(src + (i & 1048575));
    ushort4 o;
    o.x = f2bf(f.x); o.y = f2bf(f.y); o.z = f2bf(f.z); o.w = f2bf(f.w);
    *(ushort4*)(Wqkv + i) = o;
  }
}

// ---------- templated MT x NT GEMM core: C = A @ W^T, K=1024, BK=64 ----------
// 256 threads = 4 waves in 2x2. XOR-swizzled LDS (slot s in row r holds chunk s^(r&7)).
// Depth-2 counted-vmcnt pipeline (T4): raw s_barrier, loads stay in flight ACROSS
// barriers. Each stage = 6 gl_lds16/thread (4 A + 2 B). Steady state waits vmcnt(6).
// MEASURED LADDER — CLOSED FAMILIES (do not re-try):
//   128x128 tile: R1 62.2, R6 56.6 (occupancy loss > ds_read savings)
//   BK=32:        R9 61.4 (fixed per-step sync cost doubled per FLOP)
//   depth-3:      R12 54.5 (72 KB LDS -> 2 blocks/CU; occupancy > barrier savings)
//   no LDS stage: R7 attn 128 us (8x traffic — LDS staging IS cross-wave amortization)
//   n-fastest:    R8 FETCH 39->53 MB
//   grid-barrier fusion (attn+out): R14 +65 us (straggler coupling + spin traffic;
//     the HW dispatcher's inter-kernel drain/fill is CHEAPER than a software barrier)
// This config (BK=64, 128x64, depth-2, m-fastest, 3 blocks/CU) = 46.3 us on qkv.
template <int MT, int NT>
__device__ __forceinline__ void gemm_core_t(const u16* __restrict__ A, const u16* __restrict__ W,
                                            u16* As, u16* Bs,
                                            f32x4 (&acc)[MT / 32][NT / 32],
                                            int m0, int n0) {
  constexpr int AG = MT / 32, BG = NT / 32;   // staging groups AND frag count per wave
  constexpr int ASZ = MT * 64, BSZ = NT * 64; // elements per buffer
  static_assert(AG + BG == 6, "vmcnt literals assume 6 loads per stage");
  const int tid  = threadIdx.x;
  const int w    = tid >> 6, lane = tid & 63;
  const int wm   = (w >> 1) * (MT / 2), wn = (w & 1) * (NT / 2);
  const int srow = lane >> 3;
  const int slc  = ((lane & 7) ^ (srow & 7)) * 8;
  const int q4   = lane >> 4, c = lane & 15;

  auto stage = [&](int k0, int pb) {
#pragma unroll
    for (int qq = 0; qq < AG; ++qq) {
      int chunk = w * AG + qq;
      gl_lds16(A + (size_t)(m0 + chunk * 8 + srow) * 1024 + k0 + slc,
               As + pb * ASZ + chunk * 512);
    }
#pragma unroll
    for (int qq = 0; qq < BG; ++qq) {
      int chunk = w * BG + qq;
      gl_lds16(W + (size_t)(n0 + chunk * 8 + srow) * 1024 + k0 + slc,
               Bs + pb * BSZ + chunk * 512);
    }
  };

  stage(0, 0);     // 6 loads in flight
  stage(64, 1);    // 12 in flight

  for (int it = 0; it < 16; ++it) {
    const int cur = it & 1;
    // wait for stage(it)'s 6 loads; leave stage(it+1)'s 6 in flight
    if (it < 15) asm volatile("s_waitcnt vmcnt(6)" ::: "memory");
    else         asm volatile("s_waitcnt vmcnt(0)" ::: "memory");
    __builtin_amdgcn_sched_barrier(0);
    __builtin_amdgcn_s_barrier();   // all waves' stage(it) now visible

    const u16* Ab = As + cur * ASZ;
    const u16* Bb = Bs + cur * BSZ;
#pragma unroll
    for (int ks = 0; ks < 2; ++ks) {
      bf16x8 af[AG], bfr[BG];
#pragma unroll
      for (int i = 0; i < AG; ++i) {
        int row = wm + i * 16 + c;
        af[i] = *(const bf16x8*)(Ab + row * 64 + (((ks * 4 + q4) ^ (row & 7)) * 8));
      }
#pragma unroll
      for (int j = 0; j < BG; ++j) {
        int row = wn + j * 16 + c;
        bfr[j] = *(const bf16x8*)(Bb + row * 64 + (((ks * 4 + q4) ^ (row & 7)) * 8));
      }
      __builtin_amdgcn_s_setprio(1);
#pragma unroll
      for (int i = 0; i < AG; ++i)
#pragma unroll
        for (int j = 0; j < BG; ++j)
          acc[i][j] = __builtin_amdgcn_mfma_f32_16x16x32_bf16(af[i], bfr[j], acc[i][j], 0, 0, 0);
      __builtin_amdgcn_s_setprio(0);
    }

    if (it < 14) {
      __builtin_amdgcn_s_barrier();   // all waves done reading buf cur
      stage((it + 2) * 64, cur);      // refill it; lands by iteration it+2's wait
    }
  }
}

// ---------- fused QKV projection: one GEMM vs [Wq;Wk;Wv] (N=3072), tile 128x64 ----------
// Grid dim3(32m, 48n), m on x (fastest): consecutively-dispatched blocks share the same
// 128 KB W-panel. z = n0>>10 selects output: 0 -> Q (pre-scaled), 1 -> K, 2 -> V^T sigma.
__global__ void __launch_bounds__(256) qkv_gemm(const u16* __restrict__ Hb,
                                                const u16* __restrict__ Wqkv,
                                                u16* __restrict__ Q, u16* __restrict__ K,
                                                u16* __restrict__ Vt) {
  __shared__ u16 As[2 * 128 * 64];
  __shared__ u16 Bs[2 * 64 * 64];
  f32x4 acc[4][2];
#pragma unroll
  for (int i = 0; i < 4; ++i)
#pragma unroll
    for (int j = 0; j < 2; ++j) { f32x4 zv = {0.f, 0.f, 0.f, 0.f}; acc[i][j] = zv; }

  const int m0 = blockIdx.x * 128, n0g = blockIdx.y * 64;
  gemm_core_t<128, 64>(Hb, Wqkv, As, Bs, acc, m0, n0g);

  const int z = n0g >> 10, nl0 = n0g & 1023;
  const int tid = threadIdx.x, w = tid >> 6, lane = tid & 63;
  const int wm = (w >> 1) * 64, wn = (w & 1) * 32;
  const int q4 = lane >> 4, c = lane & 15;

#pragma unroll
  for (int i = 0; i < 4; ++i)
#pragma unroll
    for (int j = 0; j < 2; ++j)
#pragma unroll
      for (int r = 0; r < 4; ++r) {
        int m = m0 + wm + i * 16 + q4 * 4 + r;       // b*2048 + s
        int n = nl0 + wn + j * 16 + c;               // h*64 + d (within 1024)
        if (z == 0) {
          Q[(size_t)m * 1024 + n] = f2bf(acc[i][j][r] * QSCALE);
        } else if (z == 1) {
          K[(size_t)m * 1024 + n] = f2bf(acc[i][j][r]);
        } else {
          int b = m >> 11, s = m & 2047, h = n >> 6, d = n & 63;
          int kv = s & 127;
          int sig = ((kv >> 5) << 5) | (((kv >> 2) & 3) << 3) | (((kv >> 4) & 1) << 2) | (kv & 3);
          int sp = (s & ~127) | sig;
          Vt[(((size_t)(b * 16 + h) * 64 + d) << 11) + sp] = f2bf(acc[i][j][r]);
        }
      }
}

// ---------- flash attention, S^T orientation, fixed-max streaming softmax ----------
// 256 threads = 4 waves, each wave 32 q rows (t2 = 2 groups of 16). Block 128 q, one (b,h).
// 4 waves (R11): every wave reads the ENTIRE K/V tile from LDS regardless of q-count;
// 4 waves x 32 q halves per-CU LDS reads vs 8 waves (each kf/vf feeds 2 MFMAs).
// Depth-2 counted-vmcnt dbuf (8 loads/stage -> vmcnt(8)); ones-A MFMA l-sum on the same
// packed P registers; setprio; head-pinned XCD swizzle.
__global__ void __launch_bounds__(256, 2) attn(const u16* __restrict__ Q, const u16* __restrict__ K,
                                               const u16* __restrict__ Vt, u16* __restrict__ O) {
  __shared__ u16 Ks[2][128 * 64];   // [kv 128][d 64], swizzled (8 chunks/row)
  __shared__ u16 Vs[2][64 * 128];   // [d 64][kv' 128], swizzled (16 chunks/row)

  const int tid = threadIdx.x, w = tid >> 6, lane = tid & 63;
  const int q4 = lane >> 4, c = lane & 15;
  // head-pinned decode: bid = 8*((bh>>3)*16 + qt) + (bh&7)
  const int bid = blockIdx.x;
  const int qt = (bid >> 3) & 15;
  const int bh = ((bid >> 7) << 3) | (bid & 7);
  const int b = bh >> 4, h = bh & 15;

  const size_t qkbase = ((size_t)b * 2048) * 1024 + h * 64;   // [B,S,H,dh]
  const size_t vtbase = ((size_t)(b * 16 + h) * 64) * 2048;   // [B,H,dh,S']
  const int qbase = qt * 128 + w * 32;

  // Q fragments (B-operand: n=q=c, k=d=q4*8+j), resident all kernel
  bf16x8 qf[2][2];
#pragma unroll
  for (int t2 = 0; t2 < 2; ++t2)
#pragma unroll
    for (int ks = 0; ks < 2; ++ks)
      qf[t2][ks] = *(const bf16x8*)(Q + qkbase + (size_t)(qbase + t2 * 16 + c) * 1024 +
                                    ks * 32 + q4 * 8);

  // all-ones bf16 A-fragment for the l-sum MFMA
  BF8 onesu;
  onesu.u[0] = 0x3F803F80u; onesu.u[1] = 0x3F803F80u;
  onesu.u[2] = 0x3F803F80u; onesu.u[3] = 0x3F803F80u;
  const bf16x8 ones = onesu.v;

  f32x4 lacc[2];
  f32x4 oacc[2][4];
#pragma unroll
  for (int t2 = 0; t2 < 2; ++t2) {
    f32x4 zv = {0.f, 0.f, 0.f, 0.f};
    lacc[t2] = zv;
#pragma unroll
    for (int dt = 0; dt < 4; ++dt) oacc[t2][dt] = zv;
  }

  // staging indices: thread handles physical chunks ci = i*256 + tid, i=0..3
  int krow[4], klc[4], vrow[4], vlc[4];
#pragma unroll
  for (int i = 0; i < 4; ++i) {
    int ci = i * 256 + w * 64 + lane;
    krow[i] = ci >> 3; klc[i] = ((ci & 7) ^ (krow[i] & 7)) * 8;
    vrow[i] = ci >> 4; vlc[i] = ((ci & 15) ^ (vrow[i] & 15)) * 8;
  }

  auto stage = [&](int kt, int pb) {
#pragma unroll
    for (int i = 0; i < 4; ++i) {
      gl_lds16(K + qkbase + (size_t)(kt * 128 + krow[i]) * 1024 + klc[i],
               &Ks[pb][(i * 256 + w * 64) * 8]);
      gl_lds16(Vt + vtbase + (size_t)vrow[i] * 2048 + kt * 128 + vlc[i],
               &Vs[pb][(i * 256 + w * 64) * 8]);
    }
  };

  stage(0, 0);   // 8 loads in flight
  stage(1, 1);   // 16 in flight

  for (int kt = 0; kt < 16; ++kt) {
    const int cur = kt & 1;
    // wait for stage(kt)'s 8 loads; leave stage(kt+1)'s 8 in flight
    if (kt < 15) asm volatile("s_waitcnt vmcnt(8)" ::: "memory");
    else         asm volatile("s_waitcnt vmcnt(0)" ::: "memory");
    __builtin_amdgcn_sched_barrier(0);
    __builtin_amdgcn_s_barrier();   // all waves' stage(kt) now visible

    // S^T - M0 = K Q^T - M0 : C[row=kv (q4*4+r), col=q=c], log2 domain (Q pre-scaled)
    f32x4 sacc[2][8];
#pragma unroll
    for (int t2 = 0; t2 < 2; ++t2)
#pragma unroll
      for (int a = 0; a < 8; ++a) { f32x4 iv = {-M0, -M0, -M0, -M0}; sacc[t2][a] = iv; }
    __builtin_amdgcn_s_setprio(1);
#pragma unroll
    for (int ks = 0; ks < 2; ++ks) {
#pragma unroll
      for (int a = 0; a < 8; ++a) {
        bf16x8 kf = *(const bf16x8*)(&Ks[cur][(a * 16 + c) * 64 + (((ks * 4 + q4) ^ (c & 7)) * 8)]);
        sacc[0][a] = __builtin_amdgcn_mfma_f32_16x16x32_bf16(kf, qf[0][ks], sacc[0][a], 0, 0, 0);
        sacc[1][a] = __builtin_amdgcn_mfma_f32_16x16x32_bf16(kf, qf[1][ks], sacc[1][a], 0, 0, 0);
      }
    }
    __builtin_amdgcn_s_setprio(0);

    // p = exp2(sacc); pack high halves (truncate to bf16) straight into MFMA B-operands
    u32 pk[2][8][2];
#pragma unroll
    for (int t2 = 0; t2 < 2; ++t2) {
#pragma unroll
      for (int a = 0; a < 8; ++a) {
        FU p0, p1, p2, p3;
        p0.f = __builtin_amdgcn_exp2f(sacc[t2][a][0]);
        p1.f = __builtin_amdgcn_exp2f(sacc[t2][a][1]);
        p2.f = __builtin_amdgcn_exp2f(sacc[t2][a][2]);
        p3.f = __builtin_amdgcn_exp2f(sacc[t2][a][3]);
        pk[t2][a][0] = __builtin_amdgcn_perm(p1.u, p0.u, 0x07060302u);
        pk[t2][a][1] = __builtin_amdgcn_perm(p3.u, p2.u, 0x07060302u);
      }
    }

    // O^T += V^T P^T ; l += 1^T P^T (same pk registers -> exactly consistent)
    __builtin_amdgcn_s_setprio(1);
#pragma unroll
    for (int kch = 0; kch < 4; ++kch) {
      BF8 pf0, pf1;
      pf0.u[0] = pk[0][2 * kch][0];     pf0.u[1] = pk[0][2 * kch][1];
      pf0.u[2] = pk[0][2 * kch + 1][0]; pf0.u[3] = pk[0][2 * kch + 1][1];
      pf1.u[0] = pk[1][2 * kch][0];     pf1.u[1] = pk[1][2 * kch][1];
      pf1.u[2] = pk[1][2 * kch + 1][0]; pf1.u[3] = pk[1][2 * kch + 1][1];
      lacc[0] = __builtin_amdgcn_mfma_f32_16x16x32_bf16(ones, pf0.v, lacc[0], 0, 0, 0);
      lacc[1] = __builtin_amdgcn_mfma_f32_16x16x32_bf16(ones, pf1.v, lacc[1], 0, 0, 0);
#pragma unroll
      for (int dt = 0; dt < 4; ++dt) {
        bf16x8 vf = *(const bf16x8*)(&Vs[cur][(dt * 16 + c) * 128 + (((kch * 4 + q4) ^ c) * 8)]);
        oacc[0][dt] = __builtin_amdgcn_mfma_f32_16x16x32_bf16(vf, pf0.v, oacc[0][dt], 0, 0, 0);
        oacc[1][dt] = __builtin_amdgcn_mfma_f32_16x16x32_bf16(vf, pf1.v, oacc[1][dt], 0, 0, 0);
      }
    }
    __builtin_amdgcn_s_setprio(0);

    if (kt < 14) {
      __builtin_amdgcn_s_barrier();   // all waves done reading buf cur
      stage(kt + 2, cur);             // refill; lands by iteration kt+2's wait
    }
  }

  // lacc rows are identical (ones A): every lane holds l[its q] directly.
#pragma unroll
  for (int t2 = 0; t2 < 2; ++t2) {
    const float inv = 1.0f / lacc[t2][0];
    const size_t rowbase = qkbase + (size_t)(qbase + t2 * 16 + c) * 1024;
#pragma unroll
    for (int dt = 0; dt < 4; ++dt) {
      ushort4 o;
      o.x = f2bf(oacc[t2][dt][0] * inv);
      o.y = f2bf(oacc[t2][dt][1] * inv);
      o.z = f2bf(oacc[t2][dt][2] * inv);
      o.w = f2bf(oacc[t2][dt][3] * inv);
      *(ushort4*)(O + rowbase + dt * 16 + q4 * 4) = o;
    }
  }
}

// ---------- final projection: out = O @ Wo^T + bo (fp32 out), tile 128x64 ----------
__global__ void __launch_bounds__(256) out_gemm(const u16* __restrict__ A, const u16* __restrict__ W,
                                                const float* __restrict__ bias,
                                                float* __restrict__ Cout) {
  __shared__ u16 As[2 * 128 * 64];
  __shared__ u16 Bs[2 * 64 * 64];
  f32x4 acc[4][2];
#pragma unroll
  for (int i = 0; i < 4; ++i)
#pragma unroll
    for (int j = 0; j < 2; ++j) { f32x4 zv = {0.f, 0.f, 0.f, 0.f}; acc[i][j] = zv; }

  const int m0 = blockIdx.x * 128, n0 = blockIdx.y * 64;
  gemm_core_t<128, 64>(A, W, As, Bs, acc, m0, n0);

  const int tid = threadIdx.x, w = tid >> 6, lane = tid & 63;
  const int wm = (w >> 1) * 64, wn = (w & 1) * 32;
  const int q4 = lane >> 4, c = lane & 15;
#pragma unroll
  for (int j = 0; j < 2; ++j) {
    int n = n0 + wn + j * 16 + c;
    float bv = bias[n];
#pragma unroll
    for (int i = 0; i < 4; ++i)
#pragma unroll
      for (int r = 0; r < 4; ++r) {
        int m = m0 + wm + i * 16 + q4 * 4 + r;
        Cout[(size_t)m * 1024 + n] = acc[i][j][r] + bv;
      }
  }
}

// ---------- launch ----------
extern "C" void kernel_launch(void* const* d_in, const int* in_sizes, int n_in,
                              void* d_out, int out_size, void* d_ws, size_t ws_size,
                              hipStream_t stream) {
  const float* hs = (const float*)d_in[0];
  const float* Wq = (const float*)d_in[1];
  const float* Wk = (const float*)d_in[2];
  const float* Wv = (const float*)d_in[3];
  const float* Wo = (const float*)d_in[4];
  const float* bo = (const float*)d_in[5];
  float* out = (float*)d_out;

  u16* Hb   = (u16*)d_ws;            // 4096*1024
  u16* Wqkv = Hb + 4096 * 1024;      // [3072,1024]: Wq, Wk, Wv contiguous
  u16* Wob  = Wqkv + 3 * 1024 * 1024;
  u16* Qw   = Wob + 1024 * 1024;     // [B,S,H,dh], pre-scaled by QSCALE
  u16* Kw   = Qw + 4096 * 1024;      // [B,S,H,dh]
  u16* Vtw  = Kw + 4096 * 1024;      // [B,H,dh,S'] sigma-permuted
  u16* Ow   = Vtw + 4096 * 1024;     // [B,S,H,dh]

  cvt_all<<<8192, 256, 0, stream>>>(hs, Wq, Wk, Wv, Wo, Hb, Wqkv);

  qkv_gemm<<<dim3(32, 48), 256, 0, stream>>>(Hb, Wqkv, Qw, Kw, Vtw);
  attn<<<512, 256, 0, stream>>>(Qw, Kw, Vtw, Ow);
  out_gemm<<<dim3(32, 16), 256, 0, stream>>>(Ow, Wob, bo, out);
}

// Round 16
// 170.690 us; speedup vs baseline: 1.4391x; 1.0381x over previous
//
#include <hip/hip_runtime.h>
#include <stdint.h>

typedef unsigned short u16;
typedef unsigned int u32;
typedef __bf16 bf16x8 __attribute__((ext_vector_type(8)));
typedef float f32x4 __attribute__((ext_vector_type(4)));

#define QSCALE 0.1803368801111244f   // 64^-0.5 * log2(e): S comes out in log2 domain
#define M0 18.0f                     // fixed softmax "max" in log2 domain (true |s| <~ 12)

// ---------- helpers ----------
__device__ __forceinline__ u16 f2bf(float f) {
  union { float f; unsigned u; } v; v.f = f;
  return (u16)((v.u + 0x7FFFu + ((v.u >> 16) & 1u)) >> 16);
}

__device__ __forceinline__ void gl_lds16(const void* g, void* l) {
  typedef __attribute__((address_space(1))) void* gp_t;
  typedef __attribute__((address_space(3))) void* lp_t;
  __builtin_amdgcn_global_load_lds((gp_t)(g), (lp_t)(l), 16, 0, 0);
}

union BF8 { u32 u[4]; bf16x8 v; };
union FU { float f; u32 u; };

// ---------- fused fp32 -> bf16 converts (hidden states + 4 weight matrices) ----------
__global__ void __launch_bounds__(256) cvt_all(const float* __restrict__ hs,
                                               const float* __restrict__ Wq,
                                               const float* __restrict__ Wk,
                                               const float* __restrict__ Wv,
                                               const float* __restrict__ Wo,
                                               u16* __restrict__ Hb,
                                               u16* __restrict__ Wqkv) {
  int bid = blockIdx.x;
  if (bid < 4096) {
    int i = (bid * 256 + threadIdx.x) * 4;
    float4 f = *(const float4*)(hs + i);
    ushort4 o;
    o.x = f2bf(f.x); o.y = f2bf(f.y); o.z = f2bf(f.z); o.w = f2bf(f.w);
    *(ushort4*)(Hb + i) = o;
  } else {
    int i = ((bid - 4096) * 256 + threadIdx.x) * 4;
    int sel = i >> 20;
    const float* src = (sel == 0) ? Wq : (sel == 1) ? Wk : (sel == 2) ? Wv : Wo;
    float4 f = *(const float4*)(src + (i & 1048575));
    ushort4 o;
    o.x = f2bf(f.x); o.y = f2bf(f.y); o.z = f2bf(f.z); o.w = f2bf(f.w);
    *(ushort4*)(Wqkv + i) = o;
  }
}

// ---------- templated MT x NT GEMM core: C = A @ W^T, K=1024, BK=64 ----------
// 256 threads = 4 waves in 2x2. XOR-swizzled LDS (slot s in row r holds chunk s^(r&7)).
// Depth-2 counted-vmcnt pipeline (T4): raw s_barrier, loads stay in flight ACROSS
// barriers. Each stage = 6 gl_lds16/thread (4 A + 2 B). Steady state waits vmcnt(6).
// MEASURED LADDER — CLOSED FAMILIES (do not re-try):
//   128x128 tile: R1 62.2, R6 56.6 (occupancy loss > ds_read savings)
//   BK=32:        R9 61.4 (fixed per-step sync cost doubled per FLOP)
//   depth-3:      R12 54.5 (72 KB LDS -> 2 blocks/CU; occupancy > barrier savings)
//   no LDS stage: R7 attn 128 us (8x traffic — LDS staging IS cross-wave amortization)
//   n-fastest:    R8 FETCH 39->53 MB
//   grid-barrier fusion (attn+out): R14 +65 us (straggler coupling + spin traffic;
//     the HW dispatcher's inter-kernel drain/fill is CHEAPER than a software barrier)
// This config (BK=64, 128x64, depth-2, m-fastest, 3 blocks/CU) = 46.3 us on qkv.
template <int MT, int NT>
__device__ __forceinline__ void gemm_core_t(const u16* __restrict__ A, const u16* __restrict__ W,
                                            u16* As, u16* Bs,
                                            f32x4 (&acc)[MT / 32][NT / 32],
                                            int m0, int n0) {
  constexpr int AG = MT / 32, BG = NT / 32;   // staging groups AND frag count per wave
  constexpr int ASZ = MT * 64, BSZ = NT * 64; // elements per buffer
  static_assert(AG + BG == 6, "vmcnt literals assume 6 loads per stage");
  const int tid  = threadIdx.x;
  const int w    = tid >> 6, lane = tid & 63;
  const int wm   = (w >> 1) * (MT / 2), wn = (w & 1) * (NT / 2);
  const int srow = lane >> 3;
  const int slc  = ((lane & 7) ^ (srow & 7)) * 8;
  const int q4   = lane >> 4, c = lane & 15;

  auto stage = [&](int k0, int pb) {
#pragma unroll
    for (int qq = 0; qq < AG; ++qq) {
      int chunk = w * AG + qq;
      gl_lds16(A + (size_t)(m0 + chunk * 8 + srow) * 1024 + k0 + slc,
               As + pb * ASZ + chunk * 512);
    }
#pragma unroll
    for (int qq = 0; qq < BG; ++qq) {
      int chunk = w * BG + qq;
      gl_lds16(W + (size_t)(n0 + chunk * 8 + srow) * 1024 + k0 + slc,
               Bs + pb * BSZ + chunk * 512);
    }
  };

  stage(0, 0);     // 6 loads in flight
  stage(64, 1);    // 12 in flight

  for (int it = 0; it < 16; ++it) {
    const int cur = it & 1;
    // wait for stage(it)'s 6 loads; leave stage(it+1)'s 6 in flight
    if (it < 15) asm volatile("s_waitcnt vmcnt(6)" ::: "memory");
    else         asm volatile("s_waitcnt vmcnt(0)" ::: "memory");
    __builtin_amdgcn_sched_barrier(0);
    __builtin_amdgcn_s_barrier();   // all waves' stage(it) now visible

    const u16* Ab = As + cur * ASZ;
    const u16* Bb = Bs + cur * BSZ;
#pragma unroll
    for (int ks = 0; ks < 2; ++ks) {
      bf16x8 af[AG], bfr[BG];
#pragma unroll
      for (int i = 0; i < AG; ++i) {
        int row = wm + i * 16 + c;
        af[i] = *(const bf16x8*)(Ab + row * 64 + (((ks * 4 + q4) ^ (row & 7)) * 8));
      }
#pragma unroll
      for (int j = 0; j < BG; ++j) {
        int row = wn + j * 16 + c;
        bfr[j] = *(const bf16x8*)(Bb + row * 64 + (((ks * 4 + q4) ^ (row & 7)) * 8));
      }
      __builtin_amdgcn_s_setprio(1);
#pragma unroll
      for (int i = 0; i < AG; ++i)
#pragma unroll
        for (int j = 0; j < BG; ++j)
          acc[i][j] = __builtin_amdgcn_mfma_f32_16x16x32_bf16(af[i], bfr[j], acc[i][j], 0, 0, 0);
      __builtin_amdgcn_s_setprio(0);
    }

    if (it < 14) {
      __builtin_amdgcn_s_barrier();   // all waves done reading buf cur
      stage((it + 2) * 64, cur);      // refill it; lands by iteration it+2's wait
    }
  }
}

// ---------- fused QKV projection: one GEMM vs [Wq;Wk;Wv] (N=3072), tile 128x64 ----------
// Grid dim3(32m, 48n), m on x (fastest): consecutively-dispatched blocks share the same
// 128 KB W-panel. z = n0>>10 selects output: 0 -> Q (pre-scaled), 1 -> K, 2 -> V^T sigma.
// V^T epilogue (R16): for fixed (i,j), r=0..3 map to CONTIGUOUS sp (r only toggles kv&3,
// which sigma maps to sp bits [1:0]; base 8B-aligned) -> one ushort4 store instead of
// 4 scalar u16 stores + 4x sigma recompute. Bit-identical values at identical addresses.
__global__ void __launch_bounds__(256) qkv_gemm(const u16* __restrict__ Hb,
                                                const u16* __restrict__ Wqkv,
                                                u16* __restrict__ Q, u16* __restrict__ K,
                                                u16* __restrict__ Vt) {
  __shared__ u16 As[2 * 128 * 64];
  __shared__ u16 Bs[2 * 64 * 64];
  f32x4 acc[4][2];
#pragma unroll
  for (int i = 0; i < 4; ++i)
#pragma unroll
    for (int j = 0; j < 2; ++j) { f32x4 zv = {0.f, 0.f, 0.f, 0.f}; acc[i][j] = zv; }

  const int m0 = blockIdx.x * 128, n0g = blockIdx.y * 64;
  gemm_core_t<128, 64>(Hb, Wqkv, As, Bs, acc, m0, n0g);

  const int z = n0g >> 10, nl0 = n0g & 1023;
  const int tid = threadIdx.x, w = tid >> 6, lane = tid & 63;
  const int wm = (w >> 1) * 64, wn = (w & 1) * 32;
  const int q4 = lane >> 4, c = lane & 15;

#pragma unroll
  for (int i = 0; i < 4; ++i)
#pragma unroll
    for (int j = 0; j < 2; ++j) {
      int n = nl0 + wn + j * 16 + c;               // h*64 + d (within 1024)
      if (z == 2) {
        // packed V^T store: r=0..3 contiguous in sp
        int m = m0 + wm + i * 16 + q4 * 4;         // r = 0
        int b = m >> 11, s = m & 2047, h = n >> 6, d = n & 63;
        int kv = s & 127;                          // kv & 3 == 0 here
        int sig = ((kv >> 5) << 5) | (((kv >> 2) & 3) << 3) | (((kv >> 4) & 1) << 2);
        int sp = (s & ~127) | sig;
        ushort4 o;
        o.x = f2bf(acc[i][j][0]); o.y = f2bf(acc[i][j][1]);
        o.z = f2bf(acc[i][j][2]); o.w = f2bf(acc[i][j][3]);
        *(ushort4*)(Vt + (((size_t)(b * 16 + h) * 64 + d) << 11) + sp) = o;
      } else {
#pragma unroll
        for (int r = 0; r < 4; ++r) {
          int m = m0 + wm + i * 16 + q4 * 4 + r;   // b*2048 + s
          if (z == 0) Q[(size_t)m * 1024 + n] = f2bf(acc[i][j][r] * QSCALE);
          else        K[(size_t)m * 1024 + n] = f2bf(acc[i][j][r]);
        }
      }
    }
}

// ---------- flash attention, S^T orientation, fixed-max streaming softmax ----------
// 256 threads = 4 waves, each wave 32 q rows (t2 = 2 groups of 16). Block 128 q, one (b,h).
// 4 waves (R11): every wave reads the ENTIRE K/V tile from LDS regardless of q-count;
// 4 waves x 32 q halves per-CU LDS reads vs 8 waves (each kf/vf feeds 2 MFMAs).
// Depth-2 counted-vmcnt dbuf (8 loads/stage -> vmcnt(8)); ones-A MFMA l-sum on the same
// packed P registers; setprio; head-pinned XCD swizzle.
__global__ void __launch_bounds__(256, 2) attn(const u16* __restrict__ Q, const u16* __restrict__ K,
                                               const u16* __restrict__ Vt, u16* __restrict__ O) {
  __shared__ u16 Ks[2][128 * 64];   // [kv 128][d 64], swizzled (8 chunks/row)
  __shared__ u16 Vs[2][64 * 128];   // [d 64][kv' 128], swizzled (16 chunks/row)

  const int tid = threadIdx.x, w = tid >> 6, lane = tid & 63;
  const int q4 = lane >> 4, c = lane & 15;
  // head-pinned decode: bid = 8*((bh>>3)*16 + qt) + (bh&7)
  const int bid = blockIdx.x;
  const int qt = (bid >> 3) & 15;
  const int bh = ((bid >> 7) << 3) | (bid & 7);
  const int b = bh >> 4, h = bh & 15;

  const size_t qkbase = ((size_t)b * 2048) * 1024 + h * 64;   // [B,S,H,dh]
  const size_t vtbase = ((size_t)(b * 16 + h) * 64) * 2048;   // [B,H,dh,S']
  const int qbase = qt * 128 + w * 32;

  // Q fragments (B-operand: n=q=c, k=d=q4*8+j), resident all kernel
  bf16x8 qf[2][2];
#pragma unroll
  for (int t2 = 0; t2 < 2; ++t2)
#pragma unroll
    for (int ks = 0; ks < 2; ++ks)
      qf[t2][ks] = *(const bf16x8*)(Q + qkbase + (size_t)(qbase + t2 * 16 + c) * 1024 +
                                    ks * 32 + q4 * 8);

  // all-ones bf16 A-fragment for the l-sum MFMA
  BF8 onesu;
  onesu.u[0] = 0x3F803F80u; onesu.u[1] = 0x3F803F80u;
  onesu.u[2] = 0x3F803F80u; onesu.u[3] = 0x3F803F80u;
  const bf16x8 ones = onesu.v;

  f32x4 lacc[2];
  f32x4 oacc[2][4];
#pragma unroll
  for (int t2 = 0; t2 < 2; ++t2) {
    f32x4 zv = {0.f, 0.f, 0.f, 0.f};
    lacc[t2] = zv;
#pragma unroll
    for (int dt = 0; dt < 4; ++dt) oacc[t2][dt] = zv;
  }

  // staging indices: thread handles physical chunks ci = i*256 + tid, i=0..3
  int krow[4], klc[4], vrow[4], vlc[4];
#pragma unroll
  for (int i = 0; i < 4; ++i) {
    int ci = i * 256 + w * 64 + lane;
    krow[i] = ci >> 3; klc[i] = ((ci & 7) ^ (krow[i] & 7)) * 8;
    vrow[i] = ci >> 4; vlc[i] = ((ci & 15) ^ (vrow[i] & 15)) * 8;
  }

  auto stage = [&](int kt, int pb) {
#pragma unroll
    for (int i = 0; i < 4; ++i) {
      gl_lds16(K + qkbase + (size_t)(kt * 128 + krow[i]) * 1024 + klc[i],
               &Ks[pb][(i * 256 + w * 64) * 8]);
      gl_lds16(Vt + vtbase + (size_t)vrow[i] * 2048 + kt * 128 + vlc[i],
               &Vs[pb][(i * 256 + w * 64) * 8]);
    }
  };

  stage(0, 0);   // 8 loads in flight
  stage(1, 1);   // 16 in flight

  for (int kt = 0; kt < 16; ++kt) {
    const int cur = kt & 1;
    // wait for stage(kt)'s 8 loads; leave stage(kt+1)'s 8 in flight
    if (kt < 15) asm volatile("s_waitcnt vmcnt(8)" ::: "memory");
    else         asm volatile("s_waitcnt vmcnt(0)" ::: "memory");
    __builtin_amdgcn_sched_barrier(0);
    __builtin_amdgcn_s_barrier();   // all waves' stage(kt) now visible

    // S^T - M0 = K Q^T - M0 : C[row=kv (q4*4+r), col=q=c], log2 domain (Q pre-scaled)
    f32x4 sacc[2][8];
#pragma unroll
    for (int t2 = 0; t2 < 2; ++t2)
#pragma unroll
      for (int a = 0; a < 8; ++a) { f32x4 iv = {-M0, -M0, -M0, -M0}; sacc[t2][a] = iv; }
    __builtin_amdgcn_s_setprio(1);
#pragma unroll
    for (int ks = 0; ks < 2; ++ks) {
#pragma unroll
      for (int a = 0; a < 8; ++a) {
        bf16x8 kf = *(const bf16x8*)(&Ks[cur][(a * 16 + c) * 64 + (((ks * 4 + q4) ^ (c & 7)) * 8)]);
        sacc[0][a] = __builtin_amdgcn_mfma_f32_16x16x32_bf16(kf, qf[0][ks], sacc[0][a], 0, 0, 0);
        sacc[1][a] = __builtin_amdgcn_mfma_f32_16x16x32_bf16(kf, qf[1][ks], sacc[1][a], 0, 0, 0);
      }
    }
    __builtin_amdgcn_s_setprio(0);

    // p = exp2(sacc); pack high halves (truncate to bf16) straight into MFMA B-operands
    u32 pk[2][8][2];
#pragma unroll
    for (int t2 = 0; t2 < 2; ++t2) {
#pragma unroll
      for (int a = 0; a < 8; ++a) {
        FU p0, p1, p2, p3;
        p0.f = __builtin_amdgcn_exp2f(sacc[t2][a][0]);
        p1.f = __builtin_amdgcn_exp2f(sacc[t2][a][1]);
        p2.f = __builtin_amdgcn_exp2f(sacc[t2][a][2]);
        p3.f = __builtin_amdgcn_exp2f(sacc[t2][a][3]);
        pk[t2][a][0] = __builtin_amdgcn_perm(p1.u, p0.u, 0x07060302u);
        pk[t2][a][1] = __builtin_amdgcn_perm(p3.u, p2.u, 0x07060302u);
      }
    }

    // O^T += V^T P^T ; l += 1^T P^T (same pk registers -> exactly consistent)
    __builtin_amdgcn_s_setprio(1);
#pragma unroll
    for (int kch = 0; kch < 4; ++kch) {
      BF8 pf0, pf1;
      pf0.u[0] = pk[0][2 * kch][0];     pf0.u[1] = pk[0][2 * kch][1];
      pf0.u[2] = pk[0][2 * kch + 1][0]; pf0.u[3] = pk[0][2 * kch + 1][1];
      pf1.u[0] = pk[1][2 * kch][0];     pf1.u[1] = pk[1][2 * kch][1];
      pf1.u[2] = pk[1][2 * kch + 1][0]; pf1.u[3] = pk[1][2 * kch + 1][1];
      lacc[0] = __builtin_amdgcn_mfma_f32_16x16x32_bf16(ones, pf0.v, lacc[0], 0, 0, 0);
      lacc[1] = __builtin_amdgcn_mfma_f32_16x16x32_bf16(ones, pf1.v, lacc[1], 0, 0, 0);
#pragma unroll
      for (int dt = 0; dt < 4; ++dt) {
        bf16x8 vf = *(const bf16x8*)(&Vs[cur][(dt * 16 + c) * 128 + (((kch * 4 + q4) ^ c) * 8)]);
        oacc[0][dt] = __builtin_amdgcn_mfma_f32_16x16x32_bf16(vf, pf0.v, oacc[0][dt], 0, 0, 0);
        oacc[1][dt] = __builtin_amdgcn_mfma_f32_16x16x32_bf16(vf, pf1.v, oacc[1][dt], 0, 0, 0);
      }
    }
    __builtin_amdgcn_s_setprio(0);

    if (kt < 14) {
      __builtin_amdgcn_s_barrier();   // all waves done reading buf cur
      stage(kt + 2, cur);             // refill; lands by iteration kt+2's wait
    }
  }

  // lacc rows are identical (ones A): every lane holds l[its q] directly.
#pragma unroll
  for (int t2 = 0; t2 < 2; ++t2) {
    const float inv = 1.0f / lacc[t2][0];
    const size_t rowbase = qkbase + (size_t)(qbase + t2 * 16 + c) * 1024;
#pragma unroll
    for (int dt = 0; dt < 4; ++dt) {
      ushort4 o;
      o.x = f2bf(oacc[t2][dt][0] * inv);
      o.y = f2bf(oacc[t2][dt][1] * inv);
      o.z = f2bf(oacc[t2][dt][2] * inv);
      o.w = f2bf(oacc[t2][dt][3] * inv);
      *(ushort4*)(O + rowbase + dt * 16 + q4 * 4) = o;
    }
  }
}

// ---------- final projection: out = O @ Wo^T + bo (fp32 out), tile 128x64 ----------
__global__ void __launch_bounds__(256) out_gemm(const u16* __restrict__ A, const u16* __restrict__ W,
                                                const float* __restrict__ bias,
                                                float* __restrict__ Cout) {
  __shared__ u16 As[2 * 128 * 64];
  __shared__ u16 Bs[2 * 64 * 64];
  f32x4 acc[4][2];
#pragma unroll
  for (int i = 0; i < 4; ++i)
#pragma unroll
    for (int j = 0; j < 2; ++j) { f32x4 zv = {0.f, 0.f, 0.f, 0.f}; acc[i][j] = zv; }

  const int m0 = blockIdx.x * 128, n0 = blockIdx.y * 64;
  gemm_core_t<128, 64>(A, W, As, Bs, acc, m0, n0);

  const int tid = threadIdx.x, w = tid >> 6, lane = tid & 63;
  const int wm = (w >> 1) * 64, wn = (w & 1) * 32;
  const int q4 = lane >> 4, c = lane & 15;
#pragma unroll
  for (int j = 0; j < 2; ++j) {
    int n = n0 + wn + j * 16 + c;
    float bv = bias[n];
#pragma unroll
    for (int i = 0; i < 4; ++i)
#pragma unroll
      for (int r = 0; r < 4; ++r) {
        int m = m0 + wm + i * 16 + q4 * 4 + r;
        Cout[(size_t)m * 1024 + n] = acc[i][j][r] + bv;
      }
  }
}

// ---------- launch ----------
extern "C" void kernel_launch(void* const* d_in, const int* in_sizes, int n_in,
                              void* d_out, int out_size, void* d_ws, size_t ws_size,
                              hipStream_t stream) {
  const float* hs = (const float*)d_in[0];
  const float* Wq = (const float*)d_in[1];
  const float* Wk = (const float*)d_in[2];
  const float* Wv = (const float*)d_in[3];
  const float* Wo = (const float*)d_in[4];
  const float* bo = (const float*)d_in[5];
  float* out = (float*)d_out;

  u16* Hb   = (u16*)d_ws;            // 4096*1024
  u16* Wqkv = Hb + 4096 * 1024;      // [3072,1024]: Wq, Wk, Wv contiguous
  u16* Wob  = Wqkv + 3 * 1024 * 1024;
  u16* Qw   = Wob + 1024 * 1024;     // [B,S,H,dh], pre-scaled by QSCALE
  u16* Kw   = Qw + 4096 * 1024;      // [B,S,H,dh]
  u16* Vtw  = Kw + 4096 * 1024;      // [B,H,dh,S'] sigma-permuted
  u16* Ow   = Vtw + 4096 * 1024;     // [B,S,H,dh]

  cvt_all<<<8192, 256, 0, stream>>>(hs, Wq, Wk, Wv, Wo, Hb, Wqkv);

  qkv_gemm<<<dim3(32, 48), 256, 0, stream>>>(Hb, Wqkv, Qw, Kw, Vtw);
  attn<<<512, 256, 0, stream>>>(Qw, Kw, Vtw, Ow);
  out_gemm<<<dim3(32, 16), 256, 0, stream>>>(Ow, Wob, bo, out);
}